// Round 2
// baseline (366.071 us; speedup 1.0000x reference)
//
#include <hip/hip_runtime.h>
#include <stdint.h>

// HOPELoRALayer — B=8, S=4096, D=1024, R_TOT=104. All I/O is fp32 (per
// reference dtypes); GEMM runs in bf16 MFMA (2%-of-max threshold = ample).
// Reductions:
//   gate_scale = mean(softmax over 3) == 1/3 exactly -> gate net dead code.
//   out = X @ (base_w + (1/3) pu@diag(1+mem)@pd)^T + base_b
// mem is the fresh (zero) state -> batch-independent W0; general mem!=0 case
// kept via flags + per-batch Weff (never executed for these inputs).

typedef unsigned short ushort_t;
typedef unsigned short us8 __attribute__((ext_vector_type(8)));
typedef short short8 __attribute__((ext_vector_type(8)));
typedef float f32x4 __attribute__((ext_vector_type(4)));

__device__ __forceinline__ ushort_t f2b(float f) {  // RNE fp32->bf16
  union { float f; uint32_t i; } v; v.f = f;
  uint32_t lsb = (v.i >> 16) & 1u;
  v.i += 0x7fffu + lsb;
  return (ushort_t)(v.i >> 16);
}

__device__ __forceinline__ void async16(const void* g, void* l) {
  __builtin_amdgcn_global_load_lds(
      (const __attribute__((address_space(1))) void*)g,
      (__attribute__((address_space(3))) void*)l, 16, 0, 0);
}

// ---- x fp32 -> bf16 --------------------------------------------------------
__global__ __launch_bounds__(256) void convert_x(const float* __restrict__ x,
                                                 ushort_t* __restrict__ xb) {
  const size_t i = ((size_t)blockIdx.x * 256 + threadIdx.x) * 8;
  f32x4 a = *(const f32x4*)(x + i);
  f32x4 b = *(const f32x4*)(x + i + 4);
  us8 o;
#pragma unroll
  for (int j = 0; j < 4; j++) { o[j] = f2b(a[j]); o[4 + j] = f2b(b[j]); }
  *(us8*)(xb + i) = o;
}

// ---- flags[b] = any(mem[b,:] != 0) ----------------------------------------
__global__ void prep_flags(const uint32_t* __restrict__ mf,
                           const uint32_t* __restrict__ mm,
                           const uint32_t* __restrict__ ms,
                           int* __restrict__ flags) {
  int t = threadIdx.x;
  if (t < 8) {
    int f = 0;
    for (int r = 0; r < 8; r++)  f |= ((mf[t * 8 + r]  & 0x7fffffffu) != 0);
    for (int r = 0; r < 32; r++) f |= ((mm[t * 32 + r] & 0x7fffffffu) != 0);
    for (int r = 0; r < 64; r++) f |= ((ms[t * 64 + r] & 0x7fffffffu) != 0);
    flags[t] = f;
  }
}

// ---- W0[o][d] = base_w[o][d] + (1/3) sum_r pu[o][r] pd[r][d]  (bf16 out) ---
__global__ __launch_bounds__(128) void prep_w0(const float* __restrict__ base_w,
                                               const float* __restrict__ pu_w,
                                               const float* __restrict__ pd_w,
                                               ushort_t* __restrict__ W0) {
  const int o = blockIdx.x, t = threadIdx.x;
  __shared__ float spu[104];
  if (t < 104) spu[t] = pu_w[o * 104 + t] * (1.0f / 3.0f);
  __syncthreads();
  const int d0 = t * 8;
  float acc[8];
  f32x4 b0 = *(const f32x4*)(base_w + o * 1024 + d0);
  f32x4 b1 = *(const f32x4*)(base_w + o * 1024 + d0 + 4);
#pragma unroll
  for (int j = 0; j < 4; j++) { acc[j] = b0[j]; acc[4 + j] = b1[j]; }
  for (int r = 0; r < 104; r++) {
    f32x4 p0 = *(const f32x4*)(pd_w + r * 1024 + d0);
    f32x4 p1 = *(const f32x4*)(pd_w + r * 1024 + d0 + 4);
    float s = spu[r];
#pragma unroll
    for (int j = 0; j < 4; j++) { acc[j] += s * p0[j]; acc[4 + j] += s * p1[j]; }
  }
  us8 ov;
#pragma unroll
  for (int j = 0; j < 8; j++) ov[j] = f2b(acc[j]);
  *(us8*)(W0 + o * 1024 + d0) = ov;
}

// ---- Weff[b] = base + (1/3) sum_r pu*(1+mem[b,r])*pd  (only if mem!=0) -----
__global__ __launch_bounds__(128) void prep_delta(const float* __restrict__ base_w,
                                                  const float* __restrict__ pu_w,
                                                  const float* __restrict__ pd_w,
                                                  const float* __restrict__ mf,
                                                  const float* __restrict__ mm,
                                                  const float* __restrict__ ms,
                                                  const int* __restrict__ flags,
                                                  ushort_t* __restrict__ Weff) {
  const int o = blockIdx.x, b = blockIdx.y;
  if (flags[b] == 0) return;  // uniform across block, safe
  const int t = threadIdx.x;
  __shared__ float spu[104];
  if (t < 104) {
    float mv = (t < 8) ? mf[b * 8 + t]
             : (t < 40) ? mm[b * 32 + (t - 8)]
                        : ms[b * 64 + (t - 40)];
    spu[t] = pu_w[o * 104 + t] * (1.0f + mv) * (1.0f / 3.0f);
  }
  __syncthreads();
  const int d0 = t * 8;
  float acc[8];
  f32x4 b0 = *(const f32x4*)(base_w + o * 1024 + d0);
  f32x4 b1 = *(const f32x4*)(base_w + o * 1024 + d0 + 4);
#pragma unroll
  for (int j = 0; j < 4; j++) { acc[j] = b0[j]; acc[4 + j] = b1[j]; }
  for (int r = 0; r < 104; r++) {
    f32x4 p0 = *(const f32x4*)(pd_w + r * 1024 + d0);
    f32x4 p1 = *(const f32x4*)(pd_w + r * 1024 + d0 + 4);
    float s = spu[r];
#pragma unroll
    for (int j = 0; j < 4; j++) { acc[j] += s * p0[j]; acc[4 + j] += s * p1[j]; }
  }
  us8 ov;
#pragma unroll
  for (int j = 0; j < 8; j++) ov[j] = f2b(acc[j]);
  *(us8*)(Weff + ((size_t)b << 20) + o * 1024 + d0) = ov;
}

// ---- main GEMM: out[b, m, n] = sum_k xb[b,m,k] * W[n,k] + base_b[n] --------
// 128x128 tile, BK=32, 4 waves each 64x64 via 4x4 mfma_f32_16x16x32_bf16.
__global__ __launch_bounds__(256) void gemm_bt(const ushort_t* __restrict__ xb,
                                               const float* __restrict__ base_b,
                                               const ushort_t* __restrict__ W0,
                                               const ushort_t* __restrict__ Weff,
                                               const int* __restrict__ flags,
                                               float* __restrict__ out) {
  const int bn = blockIdx.x, bm = blockIdx.y, b = blockIdx.z;
  const ushort_t* W = flags[b] ? (Weff + ((size_t)b << 20)) : W0;

  __shared__ __align__(16) short As[128 * 32];  // [m][k], unpadded (global_load_lds)
  __shared__ __align__(16) short Bs[128 * 32];  // [n][k]

  const int t = threadIdx.x;
  const int wave = t >> 6, lane = t & 63;
  const int row16 = lane & 15, quad = lane >> 4;
  const int wm = (wave >> 1) * 64, wn = (wave & 1) * 64;

  // staging: thread t loads 8 bf16 at row (t>>2), col (t&3)*8 (plus +64-row issue)
  const ushort_t* gA = xb + (((size_t)b * 4096 + bm * 128 + (t >> 2)) << 10) + (t & 3) * 8;
  const ushort_t* gB = W + (((size_t)(bn * 128 + (t >> 2))) << 10) + (t & 3) * 8;
  char* lA = (char*)As + wave * 1024;  // HW: wave-uniform base + lane*16
  char* lB = (char*)Bs + wave * 1024;

  f32x4 acc[4][4] = {};

  for (int k0 = 0; k0 < 1024; k0 += 32) {
    async16(gA + k0, lA);
    async16(gA + k0 + (64 << 10), lA + 4096);
    async16(gB + k0, lB);
    async16(gB + k0 + (64 << 10), lB + 4096);
    __syncthreads();  // vmcnt(0) drain + barrier

    short8 af[4], bf[4];
#pragma unroll
    for (int mi = 0; mi < 4; mi++)
      af[mi] = *(const short8*)(As + (wm + mi * 16 + row16) * 32 + quad * 8);
#pragma unroll
    for (int ni = 0; ni < 4; ni++)
      bf[ni] = *(const short8*)(Bs + (wn + ni * 16 + row16) * 32 + quad * 8);
#pragma unroll
    for (int mi = 0; mi < 4; mi++)
#pragma unroll
      for (int ni = 0; ni < 4; ni++)
        acc[mi][ni] = __builtin_amdgcn_mfma_f32_16x16x32_bf16(af[mi], bf[ni],
                                                              acc[mi][ni], 0, 0, 0);
    __syncthreads();  // protect LDS before next stage
  }

  // epilogue: C/D layout col=lane&15, row=quad*4+reg (m89-verified)
#pragma unroll
  for (int ni = 0; ni < 4; ni++) {
    const int col = bn * 128 + wn + ni * 16 + row16;
    const float bb = base_b[col];
#pragma unroll
    for (int mi = 0; mi < 4; mi++) {
      const int row = bm * 128 + wm + mi * 16 + quad * 4;
#pragma unroll
      for (int i = 0; i < 4; i++) {
        out[(((size_t)b * 4096 + row + i) << 10) + col] = acc[mi][ni][i] + bb;
      }
    }
  }
}

extern "C" void kernel_launch(void* const* d_in, const int* in_sizes, int n_in,
                              void* d_out, int out_size, void* d_ws, size_t ws_size,
                              hipStream_t stream) {
  const float* x  = (const float*)d_in[0];
  const float* mf = (const float*)d_in[1];
  const float* mm = (const float*)d_in[2];
  const float* ms = (const float*)d_in[3];
  const float* base_w = (const float*)d_in[4];
  const float* base_b = (const float*)d_in[5];
  const float* pd_w = (const float*)d_in[6];
  const float* pu_w = (const float*)d_in[7];
  // d_in[8..11] (gate net) are mathematically dead: mean(softmax_3) == 1/3.

  char* ws = (char*)d_ws;
  int* flags     = (int*)ws;                                   // 32 B
  ushort_t* W0   = (ushort_t*)(ws + 4096);                     // 2 MiB
  ushort_t* xb   = (ushort_t*)(ws + 4096 + (2u << 20));        // 64 MiB
  ushort_t* Weff = (ushort_t*)(ws + 4096 + (2u << 20) + (64u << 20));  // 16 MiB, cold

  prep_flags<<<1, 64, 0, stream>>>((const uint32_t*)mf, (const uint32_t*)mm,
                                   (const uint32_t*)ms, flags);
  convert_x<<<16384, 256, 0, stream>>>(x, xb);
  prep_w0<<<1024, 128, 0, stream>>>(base_w, pu_w, pd_w, W0);
  prep_delta<<<dim3(1024, 8), 128, 0, stream>>>(base_w, pu_w, pd_w, mf, mm, ms,
                                                flags, Weff);
  gemm_bt<<<dim3(8, 32, 8), 256, 0, stream>>>(xb, base_b, W0, Weff, flags,
                                              (float*)d_out);
}

// Round 3
// 349.673 us; speedup vs baseline: 1.0469x; 1.0469x over previous
//
#include <hip/hip_runtime.h>
#include <stdint.h>

// HOPELoRALayer — B=8, S=4096, D=1024, R_TOT=104. fp32 I/O; bf16 MFMA GEMM.
// Reductions:
//   gate_scale = mean(softmax over 3) == 1/3 exactly -> gate net dead code.
//   out = X @ (base_w + (1/3) pu@diag(1+mem)@pd)^T + base_b
// mem==0 (fresh state) -> batch-independent W0; general case kept via
// per-batch flag + Weff (computed only if mem[b]!=0).
//
// R3 change: XCD-aware grid swizzle. Round-robin blockIdx->XCD means
// flat%8 picks the XCD; we map that to BATCH so each XCD streams only its
// own 8MB of x (was: each XCD streamed all 64MB -> FETCH 265MB, gemm was
// bound at 3.6TB/s effective). Within an XCD: 8-bm group outer, bn mid ->
// working set 2MB A + 2MB W0 fits the 4MB XCD L2. Preps merged to 1 kernel.

typedef unsigned short ushort_t;
typedef unsigned short us8 __attribute__((ext_vector_type(8)));
typedef short short8 __attribute__((ext_vector_type(8)));
typedef float f32x4 __attribute__((ext_vector_type(4)));

__device__ __forceinline__ ushort_t f2b(float f) {  // RNE fp32->bf16
  union { float f; uint32_t i; } v; v.f = f;
  uint32_t lsb = (v.i >> 16) & 1u;
  v.i += 0x7fffu + lsb;
  return (ushort_t)(v.i >> 16);
}

__device__ __forceinline__ void async16(const void* g, void* l) {
  __builtin_amdgcn_global_load_lds(
      (const __attribute__((address_space(1))) void*)g,
      (__attribute__((address_space(3))) void*)l, 16, 0, 0);
}

// ---- x fp32 -> bf16, batch->XCD matched to gemm ----------------------------
__global__ __launch_bounds__(256) void convert_x(const float* __restrict__ x,
                                                 ushort_t* __restrict__ xb) {
  const int flat = blockIdx.x;
  const int b = flat & 7;          // XCD-matched batch
  const int c = flat >> 3;         // 0..2047 chunk within batch
  const size_t i = (((size_t)b * 2048 + c) * 256 + threadIdx.x) * 8;
  f32x4 a0 = *(const f32x4*)(x + i);
  f32x4 a1 = *(const f32x4*)(x + i + 4);
  us8 o;
#pragma unroll
  for (int j = 0; j < 4; j++) { o[j] = f2b(a0[j]); o[4 + j] = f2b(a1[j]); }
  *(us8*)(xb + i) = o;
}

// ---- merged prep: y==0 -> W0 row; y=1..8 -> flags[b] + Weff row if mem!=0 --
__global__ __launch_bounds__(128) void prep(const float* __restrict__ base_w,
                                            const float* __restrict__ pu_w,
                                            const float* __restrict__ pd_w,
                                            const float* __restrict__ mf,
                                            const float* __restrict__ mm,
                                            const float* __restrict__ ms,
                                            ushort_t* __restrict__ W0,
                                            ushort_t* __restrict__ Weff,
                                            int* __restrict__ flags) {
  const int o = blockIdx.x, y = blockIdx.y, t = threadIdx.x;
  __shared__ float spu[104];
  __shared__ int sflag;
  ushort_t* dst;

  if (y == 0) {
    if (t < 104) spu[t] = pu_w[o * 104 + t] * (1.0f / 3.0f);
    dst = W0 + o * 1024;
    __syncthreads();
  } else {
    const int b = y - 1;
    if (t == 0) sflag = 0;
    __syncthreads();
    float mv = 0.0f;
    if (t < 104) {
      mv = (t < 8) ? mf[b * 8 + t]
         : (t < 40) ? mm[b * 32 + (t - 8)]
                    : ms[b * 64 + (t - 40)];
      if (mv != 0.0f) sflag = 1;
      spu[t] = pu_w[o * 104 + t] * (1.0f + mv) * (1.0f / 3.0f);
    }
    __syncthreads();
    if (o == 0 && t == 0) flags[b] = sflag;
    if (!sflag) return;  // block-uniform
    dst = Weff + ((size_t)b << 20) + o * 1024;
  }

  const int d0 = t * 8;
  float acc[8];
  f32x4 b0 = *(const f32x4*)(base_w + o * 1024 + d0);
  f32x4 b1 = *(const f32x4*)(base_w + o * 1024 + d0 + 4);
#pragma unroll
  for (int j = 0; j < 4; j++) { acc[j] = b0[j]; acc[4 + j] = b1[j]; }
  for (int r = 0; r < 104; r++) {
    f32x4 p0 = *(const f32x4*)(pd_w + r * 1024 + d0);
    f32x4 p1 = *(const f32x4*)(pd_w + r * 1024 + d0 + 4);
    float s = spu[r];
#pragma unroll
    for (int j = 0; j < 4; j++) { acc[j] += s * p0[j]; acc[4 + j] += s * p1[j]; }
  }
  us8 ov;
#pragma unroll
  for (int j = 0; j < 8; j++) ov[j] = f2b(acc[j]);
  *(us8*)(dst + d0) = ov;
}

// ---- main GEMM: out[b, m, n] = sum_k xb[b,m,k] * W[n,k] + base_b[n] --------
// 128x128 tile, BK=32, 4 waves each 64x64 via 4x4 mfma_f32_16x16x32_bf16.
// 1-D grid, XCD swizzle: b = flat&7 (XCD), then bm-group / bn / bm-in-group.
__global__ __launch_bounds__(256) void gemm_bt(const ushort_t* __restrict__ xb,
                                               const float* __restrict__ base_b,
                                               const ushort_t* __restrict__ W0,
                                               const ushort_t* __restrict__ Weff,
                                               const int* __restrict__ flags,
                                               float* __restrict__ out) {
  const int flat = blockIdx.x;
  const int b  = flat & 7;                 // batch == XCD
  const int i  = flat >> 3;                // 0..255
  const int g  = i >> 6;                   // 0..3  bm-group (8 tiles = 2MB A)
  const int r  = i & 63;
  const int bn = r >> 3;                   // 0..7
  const int bm = g * 8 + (r & 7);          // 0..31

  const ushort_t* W = flags[b] ? (Weff + ((size_t)b << 20)) : W0;

  __shared__ __align__(16) short As[128 * 32];  // [m][k], unpadded (global_load_lds)
  __shared__ __align__(16) short Bs[128 * 32];  // [n][k]

  const int t = threadIdx.x;
  const int wave = t >> 6, lane = t & 63;
  const int row16 = lane & 15, quad = lane >> 4;
  const int wm = (wave >> 1) * 64, wn = (wave & 1) * 64;

  // staging: thread t loads 8 bf16 at row (t>>2), col (t&3)*8 (plus +64-row issue)
  const ushort_t* gA = xb + (((size_t)b * 4096 + bm * 128 + (t >> 2)) << 10) + (t & 3) * 8;
  const ushort_t* gB = W + (((size_t)(bn * 128 + (t >> 2))) << 10) + (t & 3) * 8;
  char* lA = (char*)As + wave * 1024;  // HW dest: wave-uniform base + lane*16
  char* lB = (char*)Bs + wave * 1024;

  f32x4 acc[4][4] = {};

  for (int k0 = 0; k0 < 1024; k0 += 32) {
    async16(gA + k0, lA);
    async16(gA + k0 + (64 << 10), lA + 4096);
    async16(gB + k0, lB);
    async16(gB + k0 + (64 << 10), lB + 4096);
    __syncthreads();  // vmcnt(0) drain + barrier

    short8 af[4], bf[4];
#pragma unroll
    for (int mi = 0; mi < 4; mi++)
      af[mi] = *(const short8*)(As + (wm + mi * 16 + row16) * 32 + quad * 8);
#pragma unroll
    for (int ni = 0; ni < 4; ni++)
      bf[ni] = *(const short8*)(Bs + (wn + ni * 16 + row16) * 32 + quad * 8);
#pragma unroll
    for (int mi = 0; mi < 4; mi++)
#pragma unroll
      for (int ni = 0; ni < 4; ni++)
        acc[mi][ni] = __builtin_amdgcn_mfma_f32_16x16x32_bf16(af[mi], bf[ni],
                                                              acc[mi][ni], 0, 0, 0);
    __syncthreads();  // protect LDS before next stage
  }

  // epilogue: C/D layout col=lane&15, row=quad*4+reg (m89-verified)
#pragma unroll
  for (int ni = 0; ni < 4; ni++) {
    const int col = bn * 128 + wn + ni * 16 + row16;
    const float bb = base_b[col];
#pragma unroll
    for (int mi = 0; mi < 4; mi++) {
      const int row = bm * 128 + wm + mi * 16 + quad * 4;
#pragma unroll
      for (int i2 = 0; i2 < 4; i2++) {
        out[(((size_t)b * 4096 + row + i2) << 10) + col] = acc[mi][ni][i2] + bb;
      }
    }
  }
}

extern "C" void kernel_launch(void* const* d_in, const int* in_sizes, int n_in,
                              void* d_out, int out_size, void* d_ws, size_t ws_size,
                              hipStream_t stream) {
  const float* x  = (const float*)d_in[0];
  const float* mf = (const float*)d_in[1];
  const float* mm = (const float*)d_in[2];
  const float* ms = (const float*)d_in[3];
  const float* base_w = (const float*)d_in[4];
  const float* base_b = (const float*)d_in[5];
  const float* pd_w = (const float*)d_in[6];
  const float* pu_w = (const float*)d_in[7];
  // d_in[8..11] (gate net) are mathematically dead: mean(softmax_3) == 1/3.

  char* ws = (char*)d_ws;
  int* flags     = (int*)ws;                                   // 32 B
  ushort_t* W0   = (ushort_t*)(ws + 4096);                     // 2 MiB
  ushort_t* xb   = (ushort_t*)(ws + 4096 + (2u << 20));        // 64 MiB
  ushort_t* Weff = (ushort_t*)(ws + 4096 + (2u << 20) + (64u << 20));  // 16 MiB, cold

  prep<<<dim3(1024, 9), 128, 0, stream>>>(base_w, pu_w, pd_w, mf, mm, ms,
                                          W0, Weff, flags);
  convert_x<<<16384, 256, 0, stream>>>(x, xb);
  gemm_bt<<<2048, 256, 0, stream>>>(xb, base_b, W0, Weff, flags, (float*)d_out);
}